// Round 7
// baseline (223.249 us; speedup 1.0000x reference)
//
#include <hip/hip_runtime.h>
#include <hip/hip_bf16.h>

#define SQ 2048
#define SK 2048
#define DD 128
#define NBH 32
#define QBLK 128
#define KBLK 32
#define NKT (SK / KBLK)
#define SCALE 0.20884964425119185f
#define SCL2 (SCALE * 1.4426950408889634f)   // fold log2(e): exp2

typedef __attribute__((ext_vector_type(8))) short short8;
typedef __attribute__((ext_vector_type(4))) float f32x4;

// LDS double-buffered: K bf16 [32][272B] x2 at 0/8704; Vt bf16 [128]x80B x2 at 17408/27648
#define KPITCH 272
#define VPITCH 80
#define K0OFF 0
#define K1OFF 8704
#define V0OFF 17408
#define V1OFF 27648
#define SMEM_BYTES 37888

static __device__ __forceinline__ unsigned int pk_bf16(float lo, float hi) {
    float2 f2; f2.x = lo; f2.y = hi;
    __hip_bfloat162 h = __float22bfloat162_rn(f2);   // v_cvt_pk_bf16_f32
    union { __hip_bfloat162 h2; unsigned int u; } cv; cv.h2 = h;
    return cv.u;
}

// softmax + bf16 pack + shfl-redistribute into PV A-operand layout (R3/R5/R6-proven)
#define SOFTMAX_PACK(PA, SA_, SB_, MCa, MCb, LPART)                            \
  { float p_[8];                                                               \
    p_[0] = __builtin_amdgcn_exp2f(SA_[0]*SCL2);                               \
    p_[1] = __builtin_amdgcn_exp2f(SA_[1]*SCL2);                               \
    p_[2] = __builtin_amdgcn_exp2f(SA_[2]*SCL2);                               \
    p_[3] = __builtin_amdgcn_exp2f(SA_[3]*SCL2);                               \
    p_[4] = __builtin_amdgcn_exp2f(SB_[0]*SCL2);                               \
    p_[5] = __builtin_amdgcn_exp2f(SB_[1]*SCL2);                               \
    p_[6] = __builtin_amdgcn_exp2f(SB_[2]*SCL2);                               \
    p_[7] = __builtin_amdgcn_exp2f(SB_[3]*SCL2);                               \
    LPART += ((p_[0]+p_[1]) + (p_[2]+p_[3])) + ((p_[4]+p_[5]) + (p_[6]+p_[7]));\
    p_[0]*=MCa.x; p_[1]*=MCa.y; p_[2]*=MCa.z; p_[3]*=MCa.w;                    \
    p_[4]*=MCb.x; p_[5]*=MCb.y; p_[6]*=MCb.z; p_[7]*=MCb.w;                    \
    unsigned int P0 = pk_bf16(p_[0],p_[1]), P1 = pk_bf16(p_[2],p_[3]);         \
    unsigned int P2 = pk_bf16(p_[4],p_[5]), P3 = pk_bf16(p_[6],p_[7]);         \
    unsigned int a0 = __shfl((int)P0, sA), a2 = __shfl((int)P2, sA);           \
    unsigned int b0 = __shfl((int)P1, sA), b2 = __shfl((int)P3, sA);           \
    unsigned int c0 = __shfl((int)P0, sB), c2 = __shfl((int)P2, sB);           \
    unsigned int d0 = __shfl((int)P1, sB), d2 = __shfl((int)P3, sB);           \
    union { unsigned int u[4]; short8 v; } pb_;                                \
    pb_.u[0] = hi ? a2 : a0; pb_.u[1] = hi ? b2 : b0;                          \
    pb_.u[2] = hi ? c2 : c0; pb_.u[3] = hi ? d2 : d0;                          \
    PA = pb_.v; }

#define STAGE_SYNC()                                                           \
    asm volatile("s_waitcnt lgkmcnt(0)" ::: "memory");                         \
    __builtin_amdgcn_sched_barrier(0);                                         \
    __builtin_amdgcn_s_barrier();          /* single barrier per tile */       \
    __builtin_amdgcn_sched_barrier(0);

// compute tile from buffers (KOFF_/VOFF_), masks MC0..3; NO trailing drain
#define COMPUTE_TILE(KOFF_, VOFF_, MC0, MC1, MC2, MC3)                         \
    f32x4 s00={0,0,0,0}, s01={0,0,0,0}, s10={0,0,0,0}, s11={0,0,0,0};          \
    __builtin_amdgcn_s_setprio(1);                                             \
    _Pragma("unroll")                                                          \
    for (int ks = 0; ks < 4; ++ks) {                                           \
      short8 ka0 = *(const short8*)(smem + (KOFF_) + (c)      * KPITCH + ks*64 + 16*g); \
      short8 ka1 = *(const short8*)(smem + (KOFF_) + (16 + c) * KPITCH + ks*64 + 16*g); \
      s00 = __builtin_amdgcn_mfma_f32_16x16x32_bf16(ka0, qf0[ks], s00, 0,0,0); \
      s01 = __builtin_amdgcn_mfma_f32_16x16x32_bf16(ka1, qf0[ks], s01, 0,0,0); \
      s10 = __builtin_amdgcn_mfma_f32_16x16x32_bf16(ka0, qf1[ks], s10, 0,0,0); \
      s11 = __builtin_amdgcn_mfma_f32_16x16x32_bf16(ka1, qf1[ks], s11, 0,0,0); \
    }                                                                          \
    __builtin_amdgcn_s_setprio(0);                                             \
    short8 pa0, pa1;                                                           \
    SOFTMAX_PACK(pa0, s00, s01, MC0, MC1, l0p)                                 \
    SOFTMAX_PACK(pa1, s10, s11, MC2, MC3, l1p)                                 \
    __builtin_amdgcn_s_setprio(1);                                             \
    _Pragma("unroll")                                                          \
    for (int d8 = 0; d8 < 8; ++d8) {                                           \
      short8 vv = *(const short8*)(smem + (VOFF_) + (d8*16 + c)*VPITCH + 16*g);\
      o0[d8] = __builtin_amdgcn_mfma_f32_16x16x32_bf16(pa0, vv, o0[d8], 0,0,0);\
      o1[d8] = __builtin_amdgcn_mfma_f32_16x16x32_bf16(pa1, vv, o1[d8], 0,0,0);\
    }                                                                          \
    __builtin_amdgcn_s_setprio(0);

// ------- bf16-source body -------
#define BODY_BF(KC0,KC1,VC0,VC1, MC0,MC1,MC2,MC3,                              \
                KN0,KN1,VN0,VN1, MN0,MN1,MN2,MN3, KOFF_, VOFF_, KT)            \
  { const int kbn = ((KT) < NKT - 1) ? ((KT) + 1) * KBLK : (KT) * KBLK;        \
    KN0 = *(const short8*)(x2bb + (size_t)(kbn + kk)      * DD + kd0);         \
    KN1 = *(const short8*)(x2bb + (size_t)(kbn + kk + 16) * DD + kd0);         \
    VN0 = *(const short8*)(x2bb + (size_t)(kbn + 2*kp)     * DD + vdb);        \
    VN1 = *(const short8*)(x2bb + (size_t)(kbn + 2*kp + 1) * DD + vdb);        \
    MN0 = *(const float4*)(mq0 + kbn);                                         \
    MN1 = *(const float4*)(mq0 + kbn + 16);                                    \
    MN2 = *(const float4*)(mq1 + kbn);                                         \
    MN3 = *(const float4*)(mq1 + kbn + 16);                                    \
    *(short8*)(smem + (KOFF_) + (kk)      * KPITCH + 2*kd0) = KC0;             \
    *(short8*)(smem + (KOFF_) + (kk + 16) * KPITCH + 2*kd0) = KC1;             \
    { union { short8 s; unsigned int u[4]; } a_, b_;                           \
      a_.s = VC0; b_.s = VC1;                                                  \
      _Pragma("unroll")                                                        \
      for (int j = 0; j < 8; ++j) {                                            \
        unsigned int w = (j & 1)                                               \
            ? ((a_.u[j>>1] >> 16) | (b_.u[j>>1] & 0xffff0000u))                \
            : ((a_.u[j>>1] & 0xffffu) | (b_.u[j>>1] << 16));                   \
        *(unsigned int*)(smem + (VOFF_) + (vdb + j) * VPITCH + 4*kp) = w;      \
      } }                                                                      \
    STAGE_SYNC()                                                               \
    COMPUTE_TILE(KOFF_, VOFF_, MC0, MC1, MC2, MC3)                             \
  }

// ------- fp32-source body (fallback when ws too small) -------
#define BODY_F32(KC0,KC1,KC2,KC3, VC0,VC1,VC2,VC3, MC0,MC1,MC2,MC3,            \
                 KN0,KN1,KN2,KN3, VN0,VN1,VN2,VN3, MN0,MN1,MN2,MN3,            \
                 KOFF_, VOFF_, KT)                                             \
  { const int kbn = ((KT) < NKT - 1) ? ((KT) + 1) * KBLK : (KT) * KBLK;        \
    KN0 = *(const float4*)(x2fb + (size_t)(kbn + kk)      * DD + kd0);         \
    KN1 = *(const float4*)(x2fb + (size_t)(kbn + kk)      * DD + kd0 + 4);     \
    KN2 = *(const float4*)(x2fb + (size_t)(kbn + kk + 16) * DD + kd0);         \
    KN3 = *(const float4*)(x2fb + (size_t)(kbn + kk + 16) * DD + kd0 + 4);     \
    VN0 = *(const float4*)(x2fb + (size_t)(kbn + 2*kp)     * DD + vdb);        \
    VN1 = *(const float4*)(x2fb + (size_t)(kbn + 2*kp)     * DD + vdb + 4);    \
    VN2 = *(const float4*)(x2fb + (size_t)(kbn + 2*kp + 1) * DD + vdb);        \
    VN3 = *(const float4*)(x2fb + (size_t)(kbn + 2*kp + 1) * DD + vdb + 4);    \
    MN0 = *(const float4*)(mq0 + kbn);                                         \
    MN1 = *(const float4*)(mq0 + kbn + 16);                                    \
    MN2 = *(const float4*)(mq1 + kbn);                                         \
    MN3 = *(const float4*)(mq1 + kbn + 16);                                    \
    { union { unsigned int u[4]; short8 s; } k0_, k1_;                         \
      k0_.u[0]=pk_bf16(KC0.x,KC0.y); k0_.u[1]=pk_bf16(KC0.z,KC0.w);            \
      k0_.u[2]=pk_bf16(KC1.x,KC1.y); k0_.u[3]=pk_bf16(KC1.z,KC1.w);            \
      k1_.u[0]=pk_bf16(KC2.x,KC2.y); k1_.u[1]=pk_bf16(KC2.z,KC2.w);            \
      k1_.u[2]=pk_bf16(KC3.x,KC3.y); k1_.u[3]=pk_bf16(KC3.z,KC3.w);            \
      *(short8*)(smem + (KOFF_) + (kk)      * KPITCH + 2*kd0) = k0_.s;         \
      *(short8*)(smem + (KOFF_) + (kk + 16) * KPITCH + 2*kd0) = k1_.s; }       \
    *(unsigned int*)(smem + (VOFF_) + (vdb+0)*VPITCH + 4*kp) = pk_bf16(VC0.x, VC2.x); \
    *(unsigned int*)(smem + (VOFF_) + (vdb+1)*VPITCH + 4*kp) = pk_bf16(VC0.y, VC2.y); \
    *(unsigned int*)(smem + (VOFF_) + (vdb+2)*VPITCH + 4*kp) = pk_bf16(VC0.z, VC2.z); \
    *(unsigned int*)(smem + (VOFF_) + (vdb+3)*VPITCH + 4*kp) = pk_bf16(VC0.w, VC2.w); \
    *(unsigned int*)(smem + (VOFF_) + (vdb+4)*VPITCH + 4*kp) = pk_bf16(VC1.x, VC3.x); \
    *(unsigned int*)(smem + (VOFF_) + (vdb+5)*VPITCH + 4*kp) = pk_bf16(VC1.y, VC3.y); \
    *(unsigned int*)(smem + (VOFF_) + (vdb+6)*VPITCH + 4*kp) = pk_bf16(VC1.z, VC3.z); \
    *(unsigned int*)(smem + (VOFF_) + (vdb+7)*VPITCH + 4*kp) = pk_bf16(VC1.w, VC3.w); \
    STAGE_SYNC()                                                               \
    COMPUTE_TILE(KOFF_, VOFF_, MC0, MC1, MC2, MC3)                             \
  }

#define KERNEL_PRE()                                                           \
    __shared__ __align__(16) unsigned char smem[SMEM_BYTES];                   \
    const int tid  = threadIdx.x;                                              \
    const int lane = tid & 63, wid = tid >> 6;                                 \
    const int c = lane & 15, g = lane >> 4;                                    \
    const int bid = blockIdx.x;                                                \
    const int swz = (bid & 7) * 64 + (bid >> 3);   /* 512 = 64 x 8, bijective */\
    const int bh = swz >> 4;                                                   \
    const int qb = swz & 15;                                                   \
    const float* x1b = x1 + ((size_t)bh * SQ + (size_t)qb * QBLK) * DD;        \
    const float* mb  = mask + ((size_t)bh * SQ + (size_t)qb * QBLK) * SK;      \
    float*      outb = out + ((size_t)bh * SQ + (size_t)qb * QBLK) * DD;       \
    const int sA = c + ((g & 1) << 5);                                         \
    const int sB = sA + 16;                                                    \
    const bool hi = (g >= 2);                                                  \
    const int kk  = tid >> 4, kd0 = (tid & 15) * 8;                            \
    const int kp  = tid & 15, vdb = (tid >> 4) * 8;                            \
    const float* mq0 = mb + (size_t)(wid*16 + c) * SK + 4*g;                   \
    const float* mq1 = mq0 + (size_t)64 * SK;

#define KERNEL_QLOAD()                                                         \
    short8 qf0[4], qf1[4];                                                     \
    {  const float* q0r = x1b + (size_t)(wid*16 + c) * DD;                     \
       const float* q1r = q0r + (size_t)64 * DD;                               \
       _Pragma("unroll")                                                       \
       for (int ks = 0; ks < 4; ++ks) {                                        \
           float4 a = *(const float4*)(q0r + ks*32 + 8*g);                     \
           float4 b = *(const float4*)(q0r + ks*32 + 8*g + 4);                 \
           union { unsigned int u[4]; short8 s; } t;                           \
           t.u[0]=pk_bf16(a.x,a.y); t.u[1]=pk_bf16(a.z,a.w);                   \
           t.u[2]=pk_bf16(b.x,b.y); t.u[3]=pk_bf16(b.z,b.w);                   \
           qf0[ks]=t.s;                                                        \
           a = *(const float4*)(q1r + ks*32 + 8*g);                            \
           b = *(const float4*)(q1r + ks*32 + 8*g + 4);                        \
           t.u[0]=pk_bf16(a.x,a.y); t.u[1]=pk_bf16(a.z,a.w);                   \
           t.u[2]=pk_bf16(b.x,b.y); t.u[3]=pk_bf16(b.z,b.w);                   \
           qf1[ks]=t.s;                                                        \
       } }

#define KERNEL_EPILOGUE()                                                      \
    float l0 = l0p; l0 += __shfl_xor(l0, 16); l0 += __shfl_xor(l0, 32);        \
    float l1 = l1p; l1 += __shfl_xor(l1, 16); l1 += __shfl_xor(l1, 32);        \
    float il00 = 1.0f/__shfl(l0, 4*g+0), il01 = 1.0f/__shfl(l0, 4*g+1);        \
    float il02 = 1.0f/__shfl(l0, 4*g+2), il03 = 1.0f/__shfl(l0, 4*g+3);        \
    float il10 = 1.0f/__shfl(l1, 4*g+0), il11 = 1.0f/__shfl(l1, 4*g+1);        \
    float il12 = 1.0f/__shfl(l1, 4*g+2), il13 = 1.0f/__shfl(l1, 4*g+3);        \
    float* orow0 = outb + (size_t)(wid*16) * DD;                               \
    float* orow1 = outb + (size_t)(64 + wid*16) * DD;                          \
    _Pragma("unroll")                                                          \
    for (int d8 = 0; d8 < 8; ++d8) {                                           \
        orow0[(4*g + 0) * DD + d8*16 + c] = o0[d8][0] * il00;                  \
        orow0[(4*g + 1) * DD + d8*16 + c] = o0[d8][1] * il01;                  \
        orow0[(4*g + 2) * DD + d8*16 + c] = o0[d8][2] * il02;                  \
        orow0[(4*g + 3) * DD + d8*16 + c] = o0[d8][3] * il03;                  \
        orow1[(4*g + 0) * DD + d8*16 + c] = o1[d8][0] * il10;                  \
        orow1[(4*g + 1) * DD + d8*16 + c] = o1[d8][1] * il11;                  \
        orow1[(4*g + 2) * DD + d8*16 + c] = o1[d8][2] * il12;                  \
        orow1[(4*g + 3) * DD + d8*16 + c] = o1[d8][3] * il13;                  \
    }

__global__ __launch_bounds__(256) void cvt_x2(const float* __restrict__ src,
                                              unsigned short* __restrict__ dst,
                                              int n4) {
    int i = blockIdx.x * 256 + threadIdx.x;
    const int stride = gridDim.x * 256;
    for (; i < n4; i += stride) {
        float4 v = ((const float4*)src)[i];
        uint2 w; w.x = pk_bf16(v.x, v.y); w.y = pk_bf16(v.z, v.w);
        ((uint2*)dst)[i] = w;
    }
}

__global__ __launch_bounds__(256, 2) void fattn_bf16(
    const float* __restrict__ x1, const unsigned short* __restrict__ x2b,
    const float* __restrict__ mask, float* __restrict__ out)
{
    KERNEL_PRE()
    const unsigned short* x2bb = x2b + (size_t)bh * SK * DD;

    // tile-0 prefetch (flies under Q load)
    short8 kA0 = *(const short8*)(x2bb + (size_t)(kk)      * DD + kd0);
    short8 kA1 = *(const short8*)(x2bb + (size_t)(kk + 16) * DD + kd0);
    short8 vA0 = *(const short8*)(x2bb + (size_t)(2*kp)     * DD + vdb);
    short8 vA1 = *(const short8*)(x2bb + (size_t)(2*kp + 1) * DD + vdb);
    float4 mA0 = *(const float4*)(mq0);
    float4 mA1 = *(const float4*)(mq0 + 16);
    float4 mA2 = *(const float4*)(mq1);
    float4 mA3 = *(const float4*)(mq1 + 16);
    short8 kB0, kB1, vB0, vB1; float4 mB0, mB1, mB2, mB3;

    KERNEL_QLOAD()

    f32x4 o0[8] = {}, o1[8] = {};
    float l0p = 0.f, l1p = 0.f;

    for (int kt2 = 0; kt2 < NKT / 2; ++kt2) {
        BODY_BF(kA0,kA1,vA0,vA1, mA0,mA1,mA2,mA3,
                kB0,kB1,vB0,vB1, mB0,mB1,mB2,mB3, K0OFF, V0OFF, 2*kt2)
        BODY_BF(kB0,kB1,vB0,vB1, mB0,mB1,mB2,mB3,
                kA0,kA1,vA0,vA1, mA0,mA1,mA2,mA3, K1OFF, V1OFF, 2*kt2 + 1)
    }
    KERNEL_EPILOGUE()
}

__global__ __launch_bounds__(256, 2) void fattn_f32(
    const float* __restrict__ x1, const float* __restrict__ x2,
    const float* __restrict__ mask, float* __restrict__ out)
{
    KERNEL_PRE()
    const float* x2fb = x2 + (size_t)bh * SK * DD;

    float4 kA0 = *(const float4*)(x2fb + (size_t)(kk)      * DD + kd0);
    float4 kA1 = *(const float4*)(x2fb + (size_t)(kk)      * DD + kd0 + 4);
    float4 kA2 = *(const float4*)(x2fb + (size_t)(kk + 16) * DD + kd0);
    float4 kA3 = *(const float4*)(x2fb + (size_t)(kk + 16) * DD + kd0 + 4);
    float4 vA0 = *(const float4*)(x2fb + (size_t)(2*kp)     * DD + vdb);
    float4 vA1 = *(const float4*)(x2fb + (size_t)(2*kp)     * DD + vdb + 4);
    float4 vA2 = *(const float4*)(x2fb + (size_t)(2*kp + 1) * DD + vdb);
    float4 vA3 = *(const float4*)(x2fb + (size_t)(2*kp + 1) * DD + vdb + 4);
    float4 mA0 = *(const float4*)(mq0);
    float4 mA1 = *(const float4*)(mq0 + 16);
    float4 mA2 = *(const float4*)(mq1);
    float4 mA3 = *(const float4*)(mq1 + 16);
    float4 kB0,kB1,kB2,kB3, vB0,vB1,vB2,vB3, mB0,mB1,mB2,mB3;

    KERNEL_QLOAD()

    f32x4 o0[8] = {}, o1[8] = {};
    float l0p = 0.f, l1p = 0.f;

    for (int kt2 = 0; kt2 < NKT / 2; ++kt2) {
        BODY_F32(kA0,kA1,kA2,kA3, vA0,vA1,vA2,vA3, mA0,mA1,mA2,mA3,
                 kB0,kB1,kB2,kB3, vB0,vB1,vB2,vB3, mB0,mB1,mB2,mB3,
                 K0OFF, V0OFF, 2*kt2)
        BODY_F32(kB0,kB1,kB2,kB3, vB0,vB1,vB2,vB3, mB0,mB1,mB2,mB3,
                 kA0,kA1,kA2,kA3, vA0,vA1,vA2,vA3, mA0,mA1,mA2,mA3,
                 K1OFF, V1OFF, 2*kt2 + 1)
    }
    KERNEL_EPILOGUE()
}

extern "C" void kernel_launch(void* const* d_in, const int* in_sizes, int n_in,
                              void* d_out, int out_size, void* d_ws, size_t ws_size,
                              hipStream_t stream) {
    const float* x1   = (const float*)d_in[0];
    const float* x2   = (const float*)d_in[1];
    const float* mask = (const float*)d_in[2];
    float* out = (float*)d_out;
    const size_t need = (size_t)NBH * SK * DD * sizeof(unsigned short);
    if (ws_size >= need) {
        unsigned short* x2b = (unsigned short*)d_ws;
        cvt_x2<<<dim3(2048), dim3(256), 0, stream>>>(x2, x2b, NBH*SK*DD/4);
        fattn_bf16<<<dim3(NBH * (SQ / QBLK)), dim3(256), 0, stream>>>(x1, x2b, mask, out);
    } else {
        fattn_f32<<<dim3(NBH * (SQ / QBLK)), dim3(256), 0, stream>>>(x1, x2, mask, out);
    }
}

// Round 8
// 210.495 us; speedup vs baseline: 1.0606x; 1.0606x over previous
//
#include <hip/hip_runtime.h>
#include <hip/hip_bf16.h>

#define SQ 2048
#define SK 2048
#define DD 128
#define NBH 32
#define QBLK 128
#define KBLK 32
#define NKT (SK / KBLK)
#define SCALE 0.20884964425119185f
#define SCL2 (SCALE * 1.4426950408889634f)   // fold log2(e): exp2

typedef __attribute__((ext_vector_type(8))) short short8;
typedef __attribute__((ext_vector_type(4))) float f32x4;

// bf16 path LDS (double-buffered): K [32][272B] x2 ; Vt [128]x80B x2
#define KPITCH 272
#define VPITCH 80
#define K0OFF 0
#define K1OFF 8704
#define V0OFF 17408
#define V1OFF 27648
#define SMEM_BYTES 37888

static __device__ __forceinline__ unsigned int pk_bf16(float lo, float hi) {
    float2 f2; f2.x = lo; f2.y = hi;
    __hip_bfloat162 h = __float22bfloat162_rn(f2);   // v_cvt_pk_bf16_f32
    union { __hip_bfloat162 h2; unsigned int u; } cv; cv.h2 = h;
    return cv.u;
}

// softmax + bf16 pack + shfl-redistribute into PV A-operand layout (R3/R5/R6-proven)
#define SOFTMAX_PACK(PA, SA_, SB_, MCa, MCb, LPART)                            \
  { float p_[8];                                                               \
    p_[0] = __builtin_amdgcn_exp2f(SA_[0]*SCL2);                               \
    p_[1] = __builtin_amdgcn_exp2f(SA_[1]*SCL2);                               \
    p_[2] = __builtin_amdgcn_exp2f(SA_[2]*SCL2);                               \
    p_[3] = __builtin_amdgcn_exp2f(SA_[3]*SCL2);                               \
    p_[4] = __builtin_amdgcn_exp2f(SB_[0]*SCL2);                               \
    p_[5] = __builtin_amdgcn_exp2f(SB_[1]*SCL2);                               \
    p_[6] = __builtin_amdgcn_exp2f(SB_[2]*SCL2);                               \
    p_[7] = __builtin_amdgcn_exp2f(SB_[3]*SCL2);                               \
    LPART += ((p_[0]+p_[1]) + (p_[2]+p_[3])) + ((p_[4]+p_[5]) + (p_[6]+p_[7]));\
    p_[0]*=MCa.x; p_[1]*=MCa.y; p_[2]*=MCa.z; p_[3]*=MCa.w;                    \
    p_[4]*=MCb.x; p_[5]*=MCb.y; p_[6]*=MCb.z; p_[7]*=MCb.w;                    \
    unsigned int P0 = pk_bf16(p_[0],p_[1]), P1 = pk_bf16(p_[2],p_[3]);         \
    unsigned int P2 = pk_bf16(p_[4],p_[5]), P3 = pk_bf16(p_[6],p_[7]);         \
    unsigned int a0 = __shfl((int)P0, sA), a2 = __shfl((int)P2, sA);           \
    unsigned int b0 = __shfl((int)P1, sA), b2 = __shfl((int)P3, sA);           \
    unsigned int c0 = __shfl((int)P0, sB), c2 = __shfl((int)P2, sB);           \
    unsigned int d0 = __shfl((int)P1, sB), d2 = __shfl((int)P3, sB);           \
    union { unsigned int u[4]; short8 v; } pb_;                                \
    pb_.u[0] = hi ? a2 : a0; pb_.u[1] = hi ? b2 : b0;                          \
    pb_.u[2] = hi ? c2 : c0; pb_.u[3] = hi ? d2 : d0;                          \
    PA = pb_.v; }

#define BAR()                                                                  \
    asm volatile("s_waitcnt lgkmcnt(0)" ::: "memory");                         \
    __builtin_amdgcn_sched_barrier(0);                                         \
    __builtin_amdgcn_s_barrier();                                              \
    __builtin_amdgcn_sched_barrier(0);

// one K-tile, T14 schedule: prefetch x2(t+1) | QK | softmax | PV | stage buf^1 |
// reload mask(t+2) into its own set | single drain+barrier
#define BODY_BF(KOFFc, VOFFc, KOFFn, VOFFn, MC0, MC1, MC2, MC3, KT)            \
  {                                                                            \
    const int kbn = (((KT) < NKT - 1) ? (KT) + 1 : (KT)) * KBLK;               \
    const int kbm = (((KT) < NKT - 2) ? (KT) + 2 : (NKT - 1)) * KBLK;          \
    /* 1: x2 prefetch for t+1 (consumed by staging at step 5) */               \
    kC0 = *(const short8*)(x2bb + (size_t)(kbn + kk)      * DD + kd0);         \
    kC1 = *(const short8*)(x2bb + (size_t)(kbn + kk + 16) * DD + kd0);         \
    vC0 = *(const short8*)(x2bb + (size_t)(kbn + 2*kp)     * DD + vdb);        \
    vC1 = *(const short8*)(x2bb + (size_t)(kbn + 2*kp + 1) * DD + vdb);        \
    /* 2: QK from current buffer */                                            \
    f32x4 s00={0,0,0,0}, s01={0,0,0,0}, s10={0,0,0,0}, s11={0,0,0,0};          \
    __builtin_amdgcn_s_setprio(1);                                             \
    _Pragma("unroll")                                                          \
    for (int ks = 0; ks < 4; ++ks) {                                           \
      short8 ka0 = *(const short8*)(smem + (KOFFc) + (c)      * KPITCH + ks*64 + 16*g); \
      short8 ka1 = *(const short8*)(smem + (KOFFc) + (16 + c) * KPITCH + ks*64 + 16*g); \
      s00 = __builtin_amdgcn_mfma_f32_16x16x32_bf16(ka0, qf0[ks], s00, 0,0,0); \
      s01 = __builtin_amdgcn_mfma_f32_16x16x32_bf16(ka1, qf0[ks], s01, 0,0,0); \
      s10 = __builtin_amdgcn_mfma_f32_16x16x32_bf16(ka0, qf1[ks], s10, 0,0,0); \
      s11 = __builtin_amdgcn_mfma_f32_16x16x32_bf16(ka1, qf1[ks], s11, 0,0,0); \
    }                                                                          \
    __builtin_amdgcn_s_setprio(0);                                             \
    /* 3: softmax-lite + mask + pack + shfl */                                 \
    short8 pa0, pa1;                                                           \
    SOFTMAX_PACK(pa0, s00, s01, MC0, MC1, l0p)                                 \
    SOFTMAX_PACK(pa1, s10, s11, MC2, MC3, l1p)                                 \
    /* 4: PV from current buffer */                                            \
    __builtin_amdgcn_s_setprio(1);                                             \
    _Pragma("unroll")                                                          \
    for (int d4 = 0; d4 < 4; ++d4) {                                           \
      short8 v0 = *(const short8*)(smem + (VOFFc) + ((2*d4)*16   + c)*VPITCH + 16*g); \
      short8 v1 = *(const short8*)(smem + (VOFFc) + ((2*d4+1)*16 + c)*VPITCH + 16*g); \
      o0[2*d4]   = __builtin_amdgcn_mfma_f32_16x16x32_bf16(pa0, v0, o0[2*d4],   0,0,0); \
      o1[2*d4]   = __builtin_amdgcn_mfma_f32_16x16x32_bf16(pa1, v0, o1[2*d4],   0,0,0); \
      o0[2*d4+1] = __builtin_amdgcn_mfma_f32_16x16x32_bf16(pa0, v1, o0[2*d4+1], 0,0,0); \
      o1[2*d4+1] = __builtin_amdgcn_mfma_f32_16x16x32_bf16(pa1, v1, o1[2*d4+1], 0,0,0); \
    }                                                                          \
    __builtin_amdgcn_s_setprio(0);                                             \
    /* 5: stage t+1 into the other buffer (write latency hidden, drained at 7) */ \
    *(short8*)(smem + (KOFFn) + (kk)      * KPITCH + 2*kd0) = kC0;             \
    *(short8*)(smem + (KOFFn) + (kk + 16) * KPITCH + 2*kd0) = kC1;             \
    { union { short8 s; unsigned int u[4]; } a_, b_;                           \
      a_.s = vC0; b_.s = vC1;                                                  \
      _Pragma("unroll")                                                        \
      for (int j = 0; j < 8; ++j) {                                            \
        unsigned int w = (j & 1)                                               \
            ? ((a_.u[j>>1] >> 16) | (b_.u[j>>1] & 0xffff0000u))                \
            : ((a_.u[j>>1] & 0xffffu) | (b_.u[j>>1] << 16));                   \
        *(unsigned int*)(smem + (VOFFn) + (vdb + j) * VPITCH + 4*kp) = w;      \
      } }                                                                      \
    /* 6: reload this body's mask set with mask(t+2) — 2-tile prefetch depth */\
    MC0 = *(const float4*)(mq0 + kbm);                                         \
    MC1 = *(const float4*)(mq0 + kbm + 16);                                    \
    MC2 = *(const float4*)(mq1 + kbm);                                         \
    MC3 = *(const float4*)(mq1 + kbm + 16);                                    \
    /* 7: single drain + barrier per tile */                                   \
    BAR()                                                                      \
  }

#define KERNEL_PRE()                                                           \
    __shared__ __align__(16) unsigned char smem[SMEM_BYTES];                   \
    const int tid  = threadIdx.x;                                              \
    const int lane = tid & 63, wid = tid >> 6;                                 \
    const int c = lane & 15, g = lane >> 4;                                    \
    const int bid = blockIdx.x;                                                \
    const int swz = (bid & 7) * 64 + (bid >> 3);   /* 512 = 64 x 8, bijective */\
    const int bh = swz >> 4;                                                   \
    const int qb = swz & 15;                                                   \
    const float* x1b = x1 + ((size_t)bh * SQ + (size_t)qb * QBLK) * DD;        \
    const float* mb  = mask + ((size_t)bh * SQ + (size_t)qb * QBLK) * SK;      \
    float*      outb = out + ((size_t)bh * SQ + (size_t)qb * QBLK) * DD;       \
    const int sA = c + ((g & 1) << 5);                                         \
    const int sB = sA + 16;                                                    \
    const bool hi = (g >= 2);                                                  \
    const int kk  = tid >> 4, kd0 = (tid & 15) * 8;                            \
    const int kp  = tid & 15, vdb = (tid >> 4) * 8;                            \
    const float* mq0 = mb + (size_t)(wid*16 + c) * SK + 4*g;                   \
    const float* mq1 = mq0 + (size_t)64 * SK;

#define KERNEL_QLOAD()                                                         \
    short8 qf0[4], qf1[4];                                                     \
    {  const float* q0r = x1b + (size_t)(wid*16 + c) * DD;                     \
       const float* q1r = q0r + (size_t)64 * DD;                               \
       _Pragma("unroll")                                                       \
       for (int ks = 0; ks < 4; ++ks) {                                        \
           float4 a = *(const float4*)(q0r + ks*32 + 8*g);                     \
           float4 b = *(const float4*)(q0r + ks*32 + 8*g + 4);                 \
           union { unsigned int u[4]; short8 s; } t;                           \
           t.u[0]=pk_bf16(a.x,a.y); t.u[1]=pk_bf16(a.z,a.w);                   \
           t.u[2]=pk_bf16(b.x,b.y); t.u[3]=pk_bf16(b.z,b.w);                   \
           qf0[ks]=t.s;                                                        \
           a = *(const float4*)(q1r + ks*32 + 8*g);                            \
           b = *(const float4*)(q1r + ks*32 + 8*g + 4);                        \
           t.u[0]=pk_bf16(a.x,a.y); t.u[1]=pk_bf16(a.z,a.w);                   \
           t.u[2]=pk_bf16(b.x,b.y); t.u[3]=pk_bf16(b.z,b.w);                   \
           qf1[ks]=t.s;                                                        \
       } }

#define KERNEL_EPILOGUE()                                                      \
    float l0 = l0p; l0 += __shfl_xor(l0, 16); l0 += __shfl_xor(l0, 32);        \
    float l1 = l1p; l1 += __shfl_xor(l1, 16); l1 += __shfl_xor(l1, 32);        \
    float il00 = 1.0f/__shfl(l0, 4*g+0), il01 = 1.0f/__shfl(l0, 4*g+1);        \
    float il02 = 1.0f/__shfl(l0, 4*g+2), il03 = 1.0f/__shfl(l0, 4*g+3);        \
    float il10 = 1.0f/__shfl(l1, 4*g+0), il11 = 1.0f/__shfl(l1, 4*g+1);        \
    float il12 = 1.0f/__shfl(l1, 4*g+2), il13 = 1.0f/__shfl(l1, 4*g+3);        \
    float* orow0 = outb + (size_t)(wid*16) * DD;                               \
    float* orow1 = outb + (size_t)(64 + wid*16) * DD;                          \
    _Pragma("unroll")                                                          \
    for (int d8 = 0; d8 < 8; ++d8) {                                           \
        orow0[(4*g + 0) * DD + d8*16 + c] = o0[d8][0] * il00;                  \
        orow0[(4*g + 1) * DD + d8*16 + c] = o0[d8][1] * il01;                  \
        orow0[(4*g + 2) * DD + d8*16 + c] = o0[d8][2] * il02;                  \
        orow0[(4*g + 3) * DD + d8*16 + c] = o0[d8][3] * il03;                  \
        orow1[(4*g + 0) * DD + d8*16 + c] = o1[d8][0] * il10;                  \
        orow1[(4*g + 1) * DD + d8*16 + c] = o1[d8][1] * il11;                  \
        orow1[(4*g + 2) * DD + d8*16 + c] = o1[d8][2] * il12;                  \
        orow1[(4*g + 3) * DD + d8*16 + c] = o1[d8][3] * il13;                  \
    }

__global__ __launch_bounds__(256) void cvt_x2(const float* __restrict__ src,
                                              unsigned short* __restrict__ dst,
                                              int n4) {
    int i = blockIdx.x * 256 + threadIdx.x;
    const int stride = gridDim.x * 256;
    for (; i < n4; i += stride) {
        float4 v = ((const float4*)src)[i];
        uint2 w; w.x = pk_bf16(v.x, v.y); w.y = pk_bf16(v.z, v.w);
        ((uint2*)dst)[i] = w;
    }
}

__global__ __launch_bounds__(256, 2) void fattn_bf16(
    const float* __restrict__ x1, const unsigned short* __restrict__ x2b,
    const float* __restrict__ mask, float* __restrict__ out)
{
    KERNEL_PRE()
    const unsigned short* x2bb = x2b + (size_t)bh * SK * DD;

    // prologue: x2(0) + mask(0),mask(1) loads fly under Q load/convert
    short8 kC0 = *(const short8*)(x2bb + (size_t)(kk)      * DD + kd0);
    short8 kC1 = *(const short8*)(x2bb + (size_t)(kk + 16) * DD + kd0);
    short8 vC0 = *(const short8*)(x2bb + (size_t)(2*kp)     * DD + vdb);
    short8 vC1 = *(const short8*)(x2bb + (size_t)(2*kp + 1) * DD + vdb);
    float4 mA0 = *(const float4*)(mq0);
    float4 mA1 = *(const float4*)(mq0 + 16);
    float4 mA2 = *(const float4*)(mq1);
    float4 mA3 = *(const float4*)(mq1 + 16);
    float4 mB0 = *(const float4*)(mq0 + KBLK);
    float4 mB1 = *(const float4*)(mq0 + KBLK + 16);
    float4 mB2 = *(const float4*)(mq1 + KBLK);
    float4 mB3 = *(const float4*)(mq1 + KBLK + 16);

    KERNEL_QLOAD()

    // stage tile 0 into buffer 0
    *(short8*)(smem + K0OFF + (kk)      * KPITCH + 2*kd0) = kC0;
    *(short8*)(smem + K0OFF + (kk + 16) * KPITCH + 2*kd0) = kC1;
    { union { short8 s; unsigned int u[4]; } a_, b_;
      a_.s = vC0; b_.s = vC1;
#pragma unroll
      for (int j = 0; j < 8; ++j) {
        unsigned int w = (j & 1)
            ? ((a_.u[j>>1] >> 16) | (b_.u[j>>1] & 0xffff0000u))
            : ((a_.u[j>>1] & 0xffffu) | (b_.u[j>>1] << 16));
        *(unsigned int*)(smem + V0OFF + (vdb + j) * VPITCH + 4*kp) = w;
      } }
    BAR()

    f32x4 o0[8] = {}, o1[8] = {};
    float l0p = 0.f, l1p = 0.f;

    for (int kt2 = 0; kt2 < NKT / 2; ++kt2) {
        BODY_BF(K0OFF, V0OFF, K1OFF, V1OFF, mA0, mA1, mA2, mA3, 2*kt2)
        BODY_BF(K1OFF, V1OFF, K0OFF, V0OFF, mB0, mB1, mB2, mB3, 2*kt2 + 1)
    }
    KERNEL_EPILOGUE()
}

// -------- fp32 fallback (R6-proven structure, single buffer, 2 barriers) --------
#define F32_SYNC()                                                             \
    asm volatile("s_waitcnt lgkmcnt(0)" ::: "memory");                         \
    __builtin_amdgcn_sched_barrier(0);                                         \
    __builtin_amdgcn_s_barrier();                                              \
    __builtin_amdgcn_sched_barrier(0);

#define BODY_F32(KC0,KC1,KC2,KC3, VC0,VC1,VC2,VC3, MC0,MC1,MC2,MC3,            \
                 KN0,KN1,KN2,KN3, VN0,VN1,VN2,VN3, MN0,MN1,MN2,MN3, KT)        \
  { const int kbn = ((KT) < NKT - 1) ? ((KT) + 1) * KBLK : (KT) * KBLK;        \
    KN0 = *(const float4*)(x2fb + (size_t)(kbn + kk)      * DD + kd0);         \
    KN1 = *(const float4*)(x2fb + (size_t)(kbn + kk)      * DD + kd0 + 4);     \
    KN2 = *(const float4*)(x2fb + (size_t)(kbn + kk + 16) * DD + kd0);         \
    KN3 = *(const float4*)(x2fb + (size_t)(kbn + kk + 16) * DD + kd0 + 4);     \
    VN0 = *(const float4*)(x2fb + (size_t)(kbn + 2*kp)     * DD + vdb);        \
    VN1 = *(const float4*)(x2fb + (size_t)(kbn + 2*kp)     * DD + vdb + 4);    \
    VN2 = *(const float4*)(x2fb + (size_t)(kbn + 2*kp + 1) * DD + vdb);        \
    VN3 = *(const float4*)(x2fb + (size_t)(kbn + 2*kp + 1) * DD + vdb + 4);    \
    MN0 = *(const float4*)(mq0 + kbn);                                         \
    MN1 = *(const float4*)(mq0 + kbn + 16);                                    \
    MN2 = *(const float4*)(mq1 + kbn);                                         \
    MN3 = *(const float4*)(mq1 + kbn + 16);                                    \
    { union { unsigned int u[4]; short8 s; } k0_, k1_;                         \
      k0_.u[0]=pk_bf16(KC0.x,KC0.y); k0_.u[1]=pk_bf16(KC0.z,KC0.w);            \
      k0_.u[2]=pk_bf16(KC1.x,KC1.y); k0_.u[3]=pk_bf16(KC1.z,KC1.w);            \
      k1_.u[0]=pk_bf16(KC2.x,KC2.y); k1_.u[1]=pk_bf16(KC2.z,KC2.w);            \
      k1_.u[2]=pk_bf16(KC3.x,KC3.y); k1_.u[3]=pk_bf16(KC3.z,KC3.w);            \
      *(short8*)(smem + K0OFF + (kk)      * KPITCH + 2*kd0) = k0_.s;           \
      *(short8*)(smem + K0OFF + (kk + 16) * KPITCH + 2*kd0) = k1_.s; }         \
    *(unsigned int*)(smem + V0OFF + (vdb+0)*VPITCH + 4*kp) = pk_bf16(VC0.x, VC2.x); \
    *(unsigned int*)(smem + V0OFF + (vdb+1)*VPITCH + 4*kp) = pk_bf16(VC0.y, VC2.y); \
    *(unsigned int*)(smem + V0OFF + (vdb+2)*VPITCH + 4*kp) = pk_bf16(VC0.z, VC2.z); \
    *(unsigned int*)(smem + V0OFF + (vdb+3)*VPITCH + 4*kp) = pk_bf16(VC0.w, VC2.w); \
    *(unsigned int*)(smem + V0OFF + (vdb+4)*VPITCH + 4*kp) = pk_bf16(VC1.x, VC3.x); \
    *(unsigned int*)(smem + V0OFF + (vdb+5)*VPITCH + 4*kp) = pk_bf16(VC1.y, VC3.y); \
    *(unsigned int*)(smem + V0OFF + (vdb+6)*VPITCH + 4*kp) = pk_bf16(VC1.z, VC3.z); \
    *(unsigned int*)(smem + V0OFF + (vdb+7)*VPITCH + 4*kp) = pk_bf16(VC1.w, VC3.w); \
    F32_SYNC()                                                                 \
    f32x4 s00={0,0,0,0}, s01={0,0,0,0}, s10={0,0,0,0}, s11={0,0,0,0};          \
    _Pragma("unroll")                                                          \
    for (int ks = 0; ks < 4; ++ks) {                                           \
      short8 ka0 = *(const short8*)(smem + K0OFF + (c)      * KPITCH + ks*64 + 16*g); \
      short8 ka1 = *(const short8*)(smem + K0OFF + (16 + c) * KPITCH + ks*64 + 16*g); \
      s00 = __builtin_amdgcn_mfma_f32_16x16x32_bf16(ka0, qf0[ks], s00, 0,0,0); \
      s01 = __builtin_amdgcn_mfma_f32_16x16x32_bf16(ka1, qf0[ks], s01, 0,0,0); \
      s10 = __builtin_amdgcn_mfma_f32_16x16x32_bf16(ka0, qf1[ks], s10, 0,0,0); \
      s11 = __builtin_amdgcn_mfma_f32_16x16x32_bf16(ka1, qf1[ks], s11, 0,0,0); \
    }                                                                          \
    short8 pa0, pa1;                                                           \
    SOFTMAX_PACK(pa0, s00, s01, MC0, MC1, l0p)                                 \
    SOFTMAX_PACK(pa1, s10, s11, MC2, MC3, l1p)                                 \
    _Pragma("unroll")                                                          \
    for (int d8 = 0; d8 < 8; ++d8) {                                           \
      short8 vv = *(const short8*)(smem + V0OFF + (d8*16 + c)*VPITCH + 16*g);  \
      o0[d8] = __builtin_amdgcn_mfma_f32_16x16x32_bf16(pa0, vv, o0[d8], 0,0,0);\
      o1[d8] = __builtin_amdgcn_mfma_f32_16x16x32_bf16(pa1, vv, o1[d8], 0,0,0);\
    }                                                                          \
    F32_SYNC()                                                                 \
  }

__global__ __launch_bounds__(256, 2) void fattn_f32(
    const float* __restrict__ x1, const float* __restrict__ x2,
    const float* __restrict__ mask, float* __restrict__ out)
{
    KERNEL_PRE()
    const float* x2fb = x2 + (size_t)bh * SK * DD;

    float4 kA0 = *(const float4*)(x2fb + (size_t)(kk)      * DD + kd0);
    float4 kA1 = *(const float4*)(x2fb + (size_t)(kk)      * DD + kd0 + 4);
    float4 kA2 = *(const float4*)(x2fb + (size_t)(kk + 16) * DD + kd0);
    float4 kA3 = *(const float4*)(x2fb + (size_t)(kk + 16) * DD + kd0 + 4);
    float4 vA0 = *(const float4*)(x2fb + (size_t)(2*kp)     * DD + vdb);
    float4 vA1 = *(const float4*)(x2fb + (size_t)(2*kp)     * DD + vdb + 4);
    float4 vA2 = *(const float4*)(x2fb + (size_t)(2*kp + 1) * DD + vdb);
    float4 vA3 = *(const float4*)(x2fb + (size_t)(2*kp + 1) * DD + vdb + 4);
    float4 mA0 = *(const float4*)(mq0);
    float4 mA1 = *(const float4*)(mq0 + 16);
    float4 mA2 = *(const float4*)(mq1);
    float4 mA3 = *(const float4*)(mq1 + 16);
    float4 kB0,kB1,kB2,kB3, vB0,vB1,vB2,vB3, mB0,mB1,mB2,mB3;

    KERNEL_QLOAD()

    f32x4 o0[8] = {}, o1[8] = {};
    float l0p = 0.f, l1p = 0.f;

    for (int kt2 = 0; kt2 < NKT / 2; ++kt2) {
        BODY_F32(kA0,kA1,kA2,kA3, vA0,vA1,vA2,vA3, mA0,mA1,mA2,mA3,
                 kB0,kB1,kB2,kB3, vB0,vB1,vB2,vB3, mB0,mB1,mB2,mB3, 2*kt2)
        BODY_F32(kB0,kB1,kB2,kB3, vB0,vB1,vB2,vB3, mB0,mB1,mB2,mB3,
                 kA0,kA1,kA2,kA3, vA0,vA1,vA2,vA3, mA0,mA1,mA2,mA3, 2*kt2 + 1)
    }
    KERNEL_EPILOGUE()
}

extern "C" void kernel_launch(void* const* d_in, const int* in_sizes, int n_in,
                              void* d_out, int out_size, void* d_ws, size_t ws_size,
                              hipStream_t stream) {
    const float* x1   = (const float*)d_in[0];
    const float* x2   = (const float*)d_in[1];
    const float* mask = (const float*)d_in[2];
    float* out = (float*)d_out;
    const size_t need = (size_t)NBH * SK * DD * sizeof(unsigned short);
    if (ws_size >= need) {
        unsigned short* x2b = (unsigned short*)d_ws;
        cvt_x2<<<dim3(2048), dim3(256), 0, stream>>>(x2, x2b, NBH*SK*DD/4);
        fattn_bf16<<<dim3(NBH * (SQ / QBLK)), dim3(256), 0, stream>>>(x1, x2b, mask, out);
    } else {
        fattn_f32<<<dim3(NBH * (SQ / QBLK)), dim3(256), 0, stream>>>(x1, x2, mask, out);
    }
}

// Round 9
// 184.588 us; speedup vs baseline: 1.2094x; 1.1403x over previous
//
#include <hip/hip_runtime.h>
#include <hip/hip_bf16.h>

#define SQ 2048
#define SK 2048
#define DD 128
#define NBH 32
#define QBLK 64
#define KBLK 32
#define NKT (SK / KBLK)
#define SCALE 0.20884964425119185f
#define SCL2 (SCALE * 1.4426950408889634f)   // fold log2(e): exp2

typedef __attribute__((ext_vector_type(8))) short short8;
typedef __attribute__((ext_vector_type(4))) float f32x4;

// LDS single-buffer: K bf16 [32][272B] at 0 (8704); Vt bf16 [128]x80B at 8704 (10240)
#define KPITCH 272
#define VPITCH 80
#define VOFF 8704
#define SMEM_BYTES 18944

static __device__ __forceinline__ unsigned int pk_bf16(float lo, float hi) {
    float2 f2; f2.x = lo; f2.y = hi;
    __hip_bfloat162 h = __float22bfloat162_rn(f2);   // v_cvt_pk_bf16_f32
    union { __hip_bfloat162 h2; unsigned int u; } cv; cv.h2 = h;
    return cv.u;
}

// softmax + bf16 pack + shfl-redistribute into PV A-operand layout (R3/R5/R6-proven)
#define SOFTMAX_PACK(PA, SA_, SB_, MCa, MCb, LPART)                            \
  { float p_[8];                                                               \
    p_[0] = __builtin_amdgcn_exp2f(SA_[0]*SCL2);                               \
    p_[1] = __builtin_amdgcn_exp2f(SA_[1]*SCL2);                               \
    p_[2] = __builtin_amdgcn_exp2f(SA_[2]*SCL2);                               \
    p_[3] = __builtin_amdgcn_exp2f(SA_[3]*SCL2);                               \
    p_[4] = __builtin_amdgcn_exp2f(SB_[0]*SCL2);                               \
    p_[5] = __builtin_amdgcn_exp2f(SB_[1]*SCL2);                               \
    p_[6] = __builtin_amdgcn_exp2f(SB_[2]*SCL2);                               \
    p_[7] = __builtin_amdgcn_exp2f(SB_[3]*SCL2);                               \
    LPART += ((p_[0]+p_[1]) + (p_[2]+p_[3])) + ((p_[4]+p_[5]) + (p_[6]+p_[7]));\
    p_[0]*=MCa.x; p_[1]*=MCa.y; p_[2]*=MCa.z; p_[3]*=MCa.w;                    \
    p_[4]*=MCb.x; p_[5]*=MCb.y; p_[6]*=MCb.z; p_[7]*=MCb.w;                    \
    unsigned int P0 = pk_bf16(p_[0],p_[1]), P1 = pk_bf16(p_[2],p_[3]);         \
    unsigned int P2 = pk_bf16(p_[4],p_[5]), P3 = pk_bf16(p_[6],p_[7]);         \
    unsigned int a0 = __shfl((int)P0, sA), a2 = __shfl((int)P2, sA);           \
    unsigned int b0 = __shfl((int)P1, sA), b2 = __shfl((int)P3, sA);           \
    unsigned int c0 = __shfl((int)P0, sB), c2 = __shfl((int)P2, sB);           \
    unsigned int d0 = __shfl((int)P1, sB), d2 = __shfl((int)P3, sB);           \
    union { unsigned int u[4]; short8 v; } pb_;                                \
    pb_.u[0] = hi ? a2 : a0; pb_.u[1] = hi ? b2 : b0;                          \
    pb_.u[2] = hi ? c2 : c0; pb_.u[3] = hi ? d2 : d0;                          \
    PA = pb_.v; }

#define BAR()                                                                  \
    asm volatile("s_waitcnt lgkmcnt(0)" ::: "memory");                         \
    __builtin_amdgcn_sched_barrier(0);                                         \
    __builtin_amdgcn_s_barrier();                                              \
    __builtin_amdgcn_sched_barrier(0);

// one K-tile (R6 structure, single q-subtile): prefetch next in regs | stage |
// drain+bar | QK | softmax | PV | drain+bar
#define BODY_BF(KC0,KC1,VC0,VC1, MC0,MC1, KN0,KN1,VN0,VN1, MN0,MN1, KT)        \
  { const int kbn = ((KT) < NKT - 1) ? ((KT) + 1) * KBLK : (KT) * KBLK;        \
    KN0 = *(const short8*)(x2bb + (size_t)(kbn + kk)      * DD + kd0);         \
    KN1 = *(const short8*)(x2bb + (size_t)(kbn + kk + 16) * DD + kd0);         \
    VN0 = *(const short8*)(x2bb + (size_t)(kbn + 2*kp)     * DD + vdb);        \
    VN1 = *(const short8*)(x2bb + (size_t)(kbn + 2*kp + 1) * DD + vdb);        \
    MN0 = *(const float4*)(mq0 + kbn);                                         \
    MN1 = *(const float4*)(mq0 + kbn + 16);                                    \
    *(short8*)(smem + (kk)      * KPITCH + 2*kd0) = KC0;                       \
    *(short8*)(smem + (kk + 16) * KPITCH + 2*kd0) = KC1;                       \
    { union { short8 s; unsigned int u[4]; } a_, b_;                           \
      a_.s = VC0; b_.s = VC1;                                                  \
      _Pragma("unroll")                                                        \
      for (int j = 0; j < 8; ++j) {                                            \
        unsigned int w = (j & 1)                                               \
            ? ((a_.u[j>>1] >> 16) | (b_.u[j>>1] & 0xffff0000u))                \
            : ((a_.u[j>>1] & 0xffffu) | (b_.u[j>>1] << 16));                   \
        *(unsigned int*)(smem + VOFF + (vdb + j) * VPITCH + 4*kp) = w;         \
      } }                                                                      \
    BAR()                                                                      \
    f32x4 s00={0,0,0,0}, s01={0,0,0,0};                                        \
    __builtin_amdgcn_s_setprio(1);                                             \
    _Pragma("unroll")                                                          \
    for (int ks = 0; ks < 4; ++ks) {                                           \
      short8 ka0 = *(const short8*)(smem + (c)      * KPITCH + ks*64 + 16*g);  \
      short8 ka1 = *(const short8*)(smem + (16 + c) * KPITCH + ks*64 + 16*g);  \
      s00 = __builtin_amdgcn_mfma_f32_16x16x32_bf16(ka0, qf[ks], s00, 0,0,0);  \
      s01 = __builtin_amdgcn_mfma_f32_16x16x32_bf16(ka1, qf[ks], s01, 0,0,0);  \
    }                                                                          \
    __builtin_amdgcn_s_setprio(0);                                             \
    short8 pa;                                                                 \
    SOFTMAX_PACK(pa, s00, s01, MC0, MC1, lp)                                   \
    __builtin_amdgcn_s_setprio(1);                                             \
    _Pragma("unroll")                                                          \
    for (int d8 = 0; d8 < 8; ++d8) {                                           \
      short8 vv = *(const short8*)(smem + VOFF + (d8*16 + c)*VPITCH + 16*g);   \
      o[d8] = __builtin_amdgcn_mfma_f32_16x16x32_bf16(pa, vv, o[d8], 0,0,0);   \
    }                                                                          \
    __builtin_amdgcn_s_setprio(0);                                             \
    BAR()                                                                      \
  }

#define KERNEL_PRE()                                                           \
    __shared__ __align__(16) unsigned char smem[SMEM_BYTES];                   \
    const int tid  = threadIdx.x;                                              \
    const int lane = tid & 63, wid = tid >> 6;                                 \
    const int c = lane & 15, g = lane >> 4;                                    \
    const int bid = blockIdx.x;                                                \
    const int swz = (bid & 7) * 128 + (bid >> 3);  /* 1024 = 128 x 8, bijective */\
    const int bh = swz >> 5;                                                   \
    const int qb = swz & 31;                                                   \
    const float* x1b = x1 + ((size_t)bh * SQ + (size_t)qb * QBLK) * DD;        \
    const float* mb  = mask + ((size_t)bh * SQ + (size_t)qb * QBLK) * SK;      \
    float*      outb = out + ((size_t)bh * SQ + (size_t)qb * QBLK) * DD;       \
    const int sA = c + ((g & 1) << 5);                                         \
    const int sB = sA + 16;                                                    \
    const bool hi = (g >= 2);                                                  \
    const int kk  = tid >> 4, kd0 = (tid & 15) * 8;                            \
    const int kp  = tid & 15, vdb = (tid >> 4) * 8;                            \
    const float* mq0 = mb + (size_t)(wid*16 + c) * SK + 4*g;

#define KERNEL_QLOAD()                                                         \
    short8 qf[4];                                                              \
    {  const float* q0r = x1b + (size_t)(wid*16 + c) * DD;                     \
       _Pragma("unroll")                                                       \
       for (int ks = 0; ks < 4; ++ks) {                                        \
           float4 a = *(const float4*)(q0r + ks*32 + 8*g);                     \
           float4 b = *(const float4*)(q0r + ks*32 + 8*g + 4);                 \
           union { unsigned int u[4]; short8 s; } t;                           \
           t.u[0]=pk_bf16(a.x,a.y); t.u[1]=pk_bf16(a.z,a.w);                   \
           t.u[2]=pk_bf16(b.x,b.y); t.u[3]=pk_bf16(b.z,b.w);                   \
           qf[ks]=t.s;                                                         \
       } }

#define KERNEL_EPILOGUE()                                                      \
    float l = lp; l += __shfl_xor(l, 16); l += __shfl_xor(l, 32);              \
    float il0 = 1.0f/__shfl(l, 4*g+0), il1 = 1.0f/__shfl(l, 4*g+1);            \
    float il2 = 1.0f/__shfl(l, 4*g+2), il3 = 1.0f/__shfl(l, 4*g+3);            \
    float* orow = outb + (size_t)(wid*16) * DD;                                \
    _Pragma("unroll")                                                          \
    for (int d8 = 0; d8 < 8; ++d8) {                                           \
        orow[(4*g + 0) * DD + d8*16 + c] = o[d8][0] * il0;                     \
        orow[(4*g + 1) * DD + d8*16 + c] = o[d8][1] * il1;                     \
        orow[(4*g + 2) * DD + d8*16 + c] = o[d8][2] * il2;                     \
        orow[(4*g + 3) * DD + d8*16 + c] = o[d8][3] * il3;                     \
    }

__global__ __launch_bounds__(256) void cvt_x2(const float* __restrict__ src,
                                              unsigned short* __restrict__ dst,
                                              int n4) {
    int i = blockIdx.x * 256 + threadIdx.x;
    const int stride = gridDim.x * 256;
    for (; i < n4; i += stride) {
        float4 v = ((const float4*)src)[i];
        uint2 w; w.x = pk_bf16(v.x, v.y); w.y = pk_bf16(v.z, v.w);
        ((uint2*)dst)[i] = w;
    }
}

__global__ __launch_bounds__(256, 4) void fattn_bf16(
    const float* __restrict__ x1, const unsigned short* __restrict__ x2b,
    const float* __restrict__ mask, float* __restrict__ out)
{
    KERNEL_PRE()
    const unsigned short* x2bb = x2b + (size_t)bh * SK * DD;

    // tile-0 prefetch (flies under Q load/convert)
    short8 kA0 = *(const short8*)(x2bb + (size_t)(kk)      * DD + kd0);
    short8 kA1 = *(const short8*)(x2bb + (size_t)(kk + 16) * DD + kd0);
    short8 vA0 = *(const short8*)(x2bb + (size_t)(2*kp)     * DD + vdb);
    short8 vA1 = *(const short8*)(x2bb + (size_t)(2*kp + 1) * DD + vdb);
    float4 mA0 = *(const float4*)(mq0);
    float4 mA1 = *(const float4*)(mq0 + 16);
    short8 kB0, kB1, vB0, vB1; float4 mB0, mB1;

    KERNEL_QLOAD()

    f32x4 o[8] = {};
    float lp = 0.f;

    for (int kt2 = 0; kt2 < NKT / 2; ++kt2) {
        BODY_BF(kA0,kA1,vA0,vA1, mA0,mA1, kB0,kB1,vB0,vB1, mB0,mB1, 2*kt2)
        BODY_BF(kB0,kB1,vB0,vB1, mB0,mB1, kA0,kA1,vA0,vA1, mA0,mA1, 2*kt2 + 1)
    }
    KERNEL_EPILOGUE()
}

// -------- fp32 fallback (same structure, packs during staging) --------
#define BODY_F32(KC0,KC1,KC2,KC3, VC0,VC1,VC2,VC3, MC0,MC1,                    \
                 KN0,KN1,KN2,KN3, VN0,VN1,VN2,VN3, MN0,MN1, KT)                \
  { const int kbn = ((KT) < NKT - 1) ? ((KT) + 1) * KBLK : (KT) * KBLK;        \
    KN0 = *(const float4*)(x2fb + (size_t)(kbn + kk)      * DD + kd0);         \
    KN1 = *(const float4*)(x2fb + (size_t)(kbn + kk)      * DD + kd0 + 4);     \
    KN2 = *(const float4*)(x2fb + (size_t)(kbn + kk + 16) * DD + kd0);         \
    KN3 = *(const float4*)(x2fb + (size_t)(kbn + kk + 16) * DD + kd0 + 4);     \
    VN0 = *(const float4*)(x2fb + (size_t)(kbn + 2*kp)     * DD + vdb);        \
    VN1 = *(const float4*)(x2fb + (size_t)(kbn + 2*kp)     * DD + vdb + 4);    \
    VN2 = *(const float4*)(x2fb + (size_t)(kbn + 2*kp + 1) * DD + vdb);        \
    VN3 = *(const float4*)(x2fb + (size_t)(kbn + 2*kp + 1) * DD + vdb + 4);    \
    MN0 = *(const float4*)(mq0 + kbn);                                         \
    MN1 = *(const float4*)(mq0 + kbn + 16);                                    \
    { union { unsigned int u[4]; short8 s; } k0_, k1_;                         \
      k0_.u[0]=pk_bf16(KC0.x,KC0.y); k0_.u[1]=pk_bf16(KC0.z,KC0.w);            \
      k0_.u[2]=pk_bf16(KC1.x,KC1.y); k0_.u[3]=pk_bf16(KC1.z,KC1.w);            \
      k1_.u[0]=pk_bf16(KC2.x,KC2.y); k1_.u[1]=pk_bf16(KC2.z,KC2.w);            \
      k1_.u[2]=pk_bf16(KC3.x,KC3.y); k1_.u[3]=pk_bf16(KC3.z,KC3.w);            \
      *(short8*)(smem + (kk)      * KPITCH + 2*kd0) = k0_.s;                   \
      *(short8*)(smem + (kk + 16) * KPITCH + 2*kd0) = k1_.s; }                 \
    *(unsigned int*)(smem + VOFF + (vdb+0)*VPITCH + 4*kp) = pk_bf16(VC0.x, VC2.x); \
    *(unsigned int*)(smem + VOFF + (vdb+1)*VPITCH + 4*kp) = pk_bf16(VC0.y, VC2.y); \
    *(unsigned int*)(smem + VOFF + (vdb+2)*VPITCH + 4*kp) = pk_bf16(VC0.z, VC2.z); \
    *(unsigned int*)(smem + VOFF + (vdb+3)*VPITCH + 4*kp) = pk_bf16(VC0.w, VC2.w); \
    *(unsigned int*)(smem + VOFF + (vdb+4)*VPITCH + 4*kp) = pk_bf16(VC1.x, VC3.x); \
    *(unsigned int*)(smem + VOFF + (vdb+5)*VPITCH + 4*kp) = pk_bf16(VC1.y, VC3.y); \
    *(unsigned int*)(smem + VOFF + (vdb+6)*VPITCH + 4*kp) = pk_bf16(VC1.z, VC3.z); \
    *(unsigned int*)(smem + VOFF + (vdb+7)*VPITCH + 4*kp) = pk_bf16(VC1.w, VC3.w); \
    BAR()                                                                      \
    f32x4 s00={0,0,0,0}, s01={0,0,0,0};                                        \
    _Pragma("unroll")                                                          \
    for (int ks = 0; ks < 4; ++ks) {                                           \
      short8 ka0 = *(const short8*)(smem + (c)      * KPITCH + ks*64 + 16*g);  \
      short8 ka1 = *(const short8*)(smem + (16 + c) * KPITCH + ks*64 + 16*g);  \
      s00 = __builtin_amdgcn_mfma_f32_16x16x32_bf16(ka0, qf[ks], s00, 0,0,0);  \
      s01 = __builtin_amdgcn_mfma_f32_16x16x32_bf16(ka1, qf[ks], s01, 0,0,0);  \
    }                                                                          \
    short8 pa;                                                                 \
    SOFTMAX_PACK(pa, s00, s01, MC0, MC1, lp)                                   \
    _Pragma("unroll")                                                          \
    for (int d8 = 0; d8 < 8; ++d8) {                                           \
      short8 vv = *(const short8*)(smem + VOFF + (d8*16 + c)*VPITCH + 16*g);   \
      o[d8] = __builtin_amdgcn_mfma_f32_16x16x32_bf16(pa, vv, o[d8], 0,0,0);   \
    }                                                                          \
    BAR()                                                                      \
  }

__global__ __launch_bounds__(256, 3) void fattn_f32(
    const float* __restrict__ x1, const float* __restrict__ x2,
    const float* __restrict__ mask, float* __restrict__ out)
{
    KERNEL_PRE()
    const float* x2fb = x2 + (size_t)bh * SK * DD;

    float4 kA0 = *(const float4*)(x2fb + (size_t)(kk)      * DD + kd0);
    float4 kA1 = *(const float4*)(x2fb + (size_t)(kk)      * DD + kd0 + 4);
    float4 kA2 = *(const float4*)(x2fb + (size_t)(kk + 16) * DD + kd0);
    float4 kA3 = *(const float4*)(x2fb + (size_t)(kk + 16) * DD + kd0 + 4);
    float4 vA0 = *(const float4*)(x2fb + (size_t)(2*kp)     * DD + vdb);
    float4 vA1 = *(const float4*)(x2fb + (size_t)(2*kp)     * DD + vdb + 4);
    float4 vA2 = *(const float4*)(x2fb + (size_t)(2*kp + 1) * DD + vdb);
    float4 vA3 = *(const float4*)(x2fb + (size_t)(2*kp + 1) * DD + vdb + 4);
    float4 mA0 = *(const float4*)(mq0);
    float4 mA1 = *(const float4*)(mq0 + 16);
    float4 kB0,kB1,kB2,kB3, vB0,vB1,vB2,vB3, mB0,mB1;

    KERNEL_QLOAD()

    f32x4 o[8] = {};
    float lp = 0.f;

    for (int kt2 = 0; kt2 < NKT / 2; ++kt2) {
        BODY_F32(kA0,kA1,kA2,kA3, vA0,vA1,vA2,vA3, mA0,mA1,
                 kB0,kB1,kB2,kB3, vB0,vB1,vB2,vB3, mB0,mB1, 2*kt2)
        BODY_F32(kB0,kB1,kB2,kB3, vB0,vB1,vB2,vB3, mB0,mB1,
                 kA0,kA1,kA2,kA3, vA0,vA1,vA2,vA3, mA0,mA1, 2*kt2 + 1)
    }
    KERNEL_EPILOGUE()
}

extern "C" void kernel_launch(void* const* d_in, const int* in_sizes, int n_in,
                              void* d_out, int out_size, void* d_ws, size_t ws_size,
                              hipStream_t stream) {
    const float* x1   = (const float*)d_in[0];
    const float* x2   = (const float*)d_in[1];
    const float* mask = (const float*)d_in[2];
    float* out = (float*)d_out;
    const size_t need = (size_t)NBH * SK * DD * sizeof(unsigned short);
    if (ws_size >= need) {
        unsigned short* x2b = (unsigned short*)d_ws;
        cvt_x2<<<dim3(2048), dim3(256), 0, stream>>>(x2, x2b, NBH*SK*DD/4);
        fattn_bf16<<<dim3(NBH * (SQ / QBLK)), dim3(256), 0, stream>>>(x1, x2b, mask, out);
    } else {
        fattn_f32<<<dim3(NBH * (SQ / QBLK)), dim3(256), 0, stream>>>(x1, x2, mask, out);
    }
}